// Round 5
// baseline (211.521 us; speedup 1.0000x reference)
//
#include <hip/hip_runtime.h>

// Problem constants: B=2, S=4096, H=8, DH=64, D=512, M = B*S = 8192.
#define LOG2E 1.44269504088896340736f

typedef unsigned short u16;
typedef __bf16 bf16x4_t __attribute__((ext_vector_type(4)));
typedef __bf16 bf16x8_t __attribute__((ext_vector_type(8)));
typedef float f32x4_t __attribute__((ext_vector_type(4)));

__device__ __forceinline__ u16 f2bf(float f) {
  union { float f; unsigned int u; } v;
  v.f = f;
  unsigned int u = v.u;
  u += 0x7fffu + ((u >> 16) & 1u);
  return (u16)(u >> 16);
}

__device__ __forceinline__ f32x4_t mfma16(bf16x8_t a, bf16x8_t b, f32x4_t c) {
  return __builtin_amdgcn_mfma_f32_16x16x32_bf16(a, b, c, 0, 0, 0);
}

// async 16B global -> LDS (dest = wave-uniform base + lane*16)
__device__ __forceinline__ void gl_lds16(const u16* g, u16* l) {
  __builtin_amdgcn_global_load_lds(
      (const __attribute__((address_space(1))) unsigned int*)g,
      (__attribute__((address_space(3))) unsigned int*)l, 16, 0, 0);
}

// ---------------- cast fp32 -> bf16 (Wq pre-scaled by 0.125*log2e) ----------------
__global__ __launch_bounds__(256) void cast_all_kernel(
    const float* __restrict__ x, const float* __restrict__ wq, const float* __restrict__ wk,
    const float* __restrict__ wv, const float* __restrict__ wo,
    u16* __restrict__ xb, u16* __restrict__ wqb, u16* __restrict__ wkb,
    u16* __restrict__ wvb, u16* __restrict__ wob) {
  const int NX = 2 * 4096 * 512;
  const int NW = 512 * 512;
  int i = (blockIdx.x * 256 + threadIdx.x) * 4;
  const float* src; u16* dst; int off; float scale = 1.f;
  if (i < NX)               { src = x;  dst = xb;  off = i; }
  else if (i < NX + NW)     { src = wq; dst = wqb; off = i - NX; scale = 0.125f * LOG2E; }
  else if (i < NX + 2 * NW) { src = wk; dst = wkb; off = i - NX - NW; }
  else if (i < NX + 3 * NW) { src = wv; dst = wvb; off = i - NX - 2 * NW; }
  else                      { src = wo; dst = wob; off = i - NX - 3 * NW; }
  float4 f = *(const float4*)(src + off);
  unsigned int lo = (unsigned int)f2bf(f.x * scale) | ((unsigned int)f2bf(f.y * scale) << 16);
  unsigned int hi = (unsigned int)f2bf(f.z * scale) | ((unsigned int)f2bf(f.w * scale) << 16);
  uint2 o; o.x = lo; o.y = hi;
  *(uint2*)(dst + off) = o;
}

// ---------------- GEMM: C[M,N] = A[M,512] @ Bt[N,512]^T (both bf16, K-contig) ----------------
// MODE 0: bf16 row-major C. MODE 1: V^T store. MODE 2: fp32 + bias.
// Register-prefetch pipeline: tile k+1 loaded into VGPRs during compute of tile k.
template <int MODE>
__device__ __forceinline__ void gemm_core(const u16* __restrict__ A, const u16* __restrict__ Bt,
                                          void* __restrict__ Cout, const float* __restrict__ bias,
                                          int Mbase, int Nbase) {
  __shared__ __align__(16) u16 As[128][40];
  __shared__ __align__(16) u16 Bs[128][40];
  const int t = threadIdx.x;
  const int wave = t >> 6, lane = t & 63;
  const int r = lane & 15, qd = lane >> 4;
  const int wm = wave & 1, wn = wave >> 1;
  const int lr = t >> 2;
  const int lc = (t & 3) * 8;

  f32x4_t acc[4][4];
#pragma unroll
  for (int i = 0; i < 4; i++)
#pragma unroll
    for (int j = 0; j < 4; j++) { f32x4_t z = {0.f, 0.f, 0.f, 0.f}; acc[i][j] = z; }

  const u16* pa0 = A  + (Mbase + lr) * 512 + lc;
  const u16* pa1 = A  + (Mbase + 64 + lr) * 512 + lc;
  const u16* pb0 = Bt + (Nbase + lr) * 512 + lc;
  const u16* pb1 = Bt + (Nbase + 64 + lr) * 512 + lc;

  uint4 ra0 = *(const uint4*)(pa0);
  uint4 ra1 = *(const uint4*)(pa1);
  uint4 rb0 = *(const uint4*)(pb0);
  uint4 rb1 = *(const uint4*)(pb1);

  for (int k0 = 0; k0 < 512; k0 += 32) {
    *(uint4*)&As[lr][lc]      = ra0;
    *(uint4*)&As[64 + lr][lc] = ra1;
    *(uint4*)&Bs[lr][lc]      = rb0;
    *(uint4*)&Bs[64 + lr][lc] = rb1;
    __syncthreads();
    if (k0 < 480) {
      ra0 = *(const uint4*)(pa0 + k0 + 32);
      ra1 = *(const uint4*)(pa1 + k0 + 32);
      rb0 = *(const uint4*)(pb0 + k0 + 32);
      rb1 = *(const uint4*)(pb1 + k0 + 32);
    }
    bf16x8_t af[4], bfr[4];
#pragma unroll
    for (int i = 0; i < 4; i++) af[i]  = *(const bf16x8_t*)&As[wm * 64 + i * 16 + r][qd * 8];
#pragma unroll
    for (int j = 0; j < 4; j++) bfr[j] = *(const bf16x8_t*)&Bs[wn * 64 + j * 16 + r][qd * 8];
#pragma unroll
    for (int i = 0; i < 4; i++)
#pragma unroll
      for (int j = 0; j < 4; j++) acc[i][j] = mfma16(af[i], bfr[j], acc[i][j]);
    __syncthreads();
  }

  float bv[4];
  if (MODE == 2) {
#pragma unroll
    for (int j = 0; j < 4; j++) bv[j] = bias[Nbase + wn * 64 + j * 16 + r];
  }
#pragma unroll
  for (int i = 0; i < 4; i++) {
#pragma unroll
    for (int reg = 0; reg < 4; reg++) {
      int gr = Mbase + wm * 64 + i * 16 + qd * 4 + reg;
#pragma unroll
      for (int j = 0; j < 4; j++) {
        int gc = Nbase + wn * 64 + j * 16 + r;
        float val = acc[i][j][reg];
        if (MODE == 2) {
          ((float*)Cout)[gr * 512 + gc] = val + bv[j];
        } else if (MODE == 1) {
          int bb = gc >> 12, ss = gc & 4095;
          ((__bf16*)Cout)[((long)(bb * 512 + gr)) * 4096 + ss] = (__bf16)val;
        } else {
          ((__bf16*)Cout)[gr * 512 + gc] = (__bf16)val;
        }
      }
    }
  }
}

__global__ __launch_bounds__(256) void gemm_qkv_kernel(
    const u16* __restrict__ X,
    const u16* __restrict__ Wq, const u16* __restrict__ Wk, const u16* __restrict__ Wv,
    u16* __restrict__ Q, u16* __restrict__ K, u16* __restrict__ Vt) {
  if (blockIdx.z == 0)
    gemm_core<0>(X, Wq, Q, nullptr, blockIdx.x * 128, blockIdx.y * 128);
  else if (blockIdx.z == 1)
    gemm_core<0>(X, Wk, K, nullptr, blockIdx.x * 128, blockIdx.y * 128);
  else
    gemm_core<1>(Wv, X, Vt, nullptr, blockIdx.y * 128, blockIdx.x * 128);
}

__global__ __launch_bounds__(256) void gemm_out_kernel(
    const u16* __restrict__ Aat, const u16* __restrict__ Wo,
    float* __restrict__ Out, const float* __restrict__ bo) {
  gemm_core<2>(Aat, Wo, Out, bo, blockIdx.x * 128, blockIdx.y * 128);
}

// ---------------- flash attention v4: prefetch double-buffered K/V ----------------
// grid (32, 16), block 256 (4 waves). Wave = (g = wave&1 -> 64-query group,
// kv = wave>>1 -> 2048-key half). Transposed scores (A=K, B=Q) -> b64 P writes.
// Single barrier per tile; K/V for tile t+1 issued (global_load_lds) right after
// the barrier of tile t, so load latency hides under compute of tile t.
// LDS: Ks[2][2][4096] 32K + Vs[2][2][4096] 32K + Ps[4][2048] 16K = 80 KiB -> 2 blocks/CU.
__global__ __launch_bounds__(256, 2) void attn_kernel(
    const u16* __restrict__ Q, const u16* __restrict__ K, const u16* __restrict__ Vt,
    u16* __restrict__ Oattn) {
  __shared__ __align__(16) u16 Ks[2][2][4096];
  __shared__ __align__(16) u16 Vs[2][2][4096];
  __shared__ __align__(16) u16 Ps[4][2048];   // per-wave P: 64 q x 32 k, rows 32 u16 (4 chunks)

  const int t = threadIdx.x;
  const int wave = t >> 6, lane = t & 63;
  const int r = lane & 15, qd = lane >> 4;
  const int g = wave & 1, kv = wave >> 1;
  const int bh = blockIdx.y;
  const int b = bh >> 3, h = bh & 7;
  const long bbase = (long)b * 4096 * 512;
  const int q0 = blockIdx.x * 128;

  const int sw = r & 7;
  const int ck0 = (qd ^ sw) * 8;          // K/V row chunk slots (rows 64 u16, 8 chunks)
  const int ck1 = ((qd + 4) ^ sw) * 8;
  const int psw = r & 3;                  // Ps rows 32 u16, 4 chunks
  const int pck = (qd ^ psw) * 8;

  // Q as B-operand fragments (resident)
  bf16x8_t qf[4][2];
#pragma unroll
  for (int qa = 0; qa < 4; qa++) {
    const u16* qp = Q + bbase + (long)(q0 + g * 64 + qa * 16 + r) * 512 + h * 64 + qd * 8;
    qf[qa][0] = *(const bf16x8_t*)(qp);
    qf[qa][1] = *(const bf16x8_t*)(qp + 32);
  }

  f32x4_t accO[4][4];
  float Lacc[4];
#pragma unroll
  for (int qa = 0; qa < 4; qa++) {
    f32x4_t z = {0.f, 0.f, 0.f, 0.f};
    Lacc[qa] = 0.f;
#pragma unroll
    for (int nt = 0; nt < 4; nt++) accO[qa][nt] = z;
  }

  // staging: wave stages rows g*32..+31 of its kv-half's K and V tiles
  const int rr = lane >> 3;
  const int cc = (lane & 7) ^ rr;
  const u16* kgb = K + bbase + (long)(kv * 2048 + g * 32 + rr) * 512 + h * 64 + cc * 8;
  const u16* vgb = Vt + ((long)(b * 512 + h * 64 + g * 32 + rr)) * 4096 + kv * 2048 + cc * 8;

  // prologue: issue tile 0 into buf 0
#pragma unroll
  for (int i = 0; i < 4; i++) gl_lds16(kgb + (long)i * 8 * 512, &Ks[kv][0][g * 2048] + i * 512);
#pragma unroll
  for (int i = 0; i < 4; i++) gl_lds16(vgb + i * 8 * 4096, &Vs[kv][0][g * 2048] + i * 512);

  for (int it = 0; it < 32; it++) {
    const int buf = it & 1;
    __syncthreads();   // drains this tile's loads (issued one iter ago -> already done)

    if (it < 31) {     // prefetch tile it+1 (safe: all waves are past compute(it-1))
      const int nb = (it + 1) & 1;
      const long ko = (long)(it + 1) * 64;
#pragma unroll
      for (int i = 0; i < 4; i++)
        gl_lds16(kgb + (ko + i * 8) * 512, &Ks[kv][nb][g * 2048] + i * 512);
#pragma unroll
      for (int i = 0; i < 4; i++)
        gl_lds16(vgb + ko + (long)i * 8 * 4096, &Vs[kv][nb][g * 2048] + i * 512);
    }

    // K as A-operand fragments
    bf16x8_t kf[4][2];
#pragma unroll
    for (int nt = 0; nt < 4; nt++) {
      const u16* kb = &Ks[kv][buf][(nt * 16 + r) * 64];
      kf[nt][0] = *(const bf16x8_t*)(kb + ck0);
      kf[nt][1] = *(const bf16x8_t*)(kb + ck1);
    }

    // transposed scores St[m=key][n=query]
    f32x4_t St[4][4];
#pragma unroll
    for (int qa = 0; qa < 4; qa++)
#pragma unroll
      for (int nt = 0; nt < 4; nt++) {
        f32x4_t z = {0.f, 0.f, 0.f, 0.f};
        z = mfma16(kf[nt][0], qf[qa][0], z);
        z = mfma16(kf[nt][1], qf[qa][1], z);
        St[qa][nt] = z;
      }

    // exp2 + L accumulate (scores pre-scaled by 0.125*log2e)
    bf16x4_t pk[4][4];
#pragma unroll
    for (int qa = 0; qa < 4; qa++)
#pragma unroll
      for (int nt = 0; nt < 4; nt++) {
        float p0 = __builtin_amdgcn_exp2f(St[qa][nt][0]);
        float p1 = __builtin_amdgcn_exp2f(St[qa][nt][1]);
        float p2 = __builtin_amdgcn_exp2f(St[qa][nt][2]);
        float p3 = __builtin_amdgcn_exp2f(St[qa][nt][3]);
        Lacc[qa] += (p0 + p1) + (p2 + p3);
        pk[qa][nt][0] = (__bf16)p0; pk[qa][nt][1] = (__bf16)p1;
        pk[qa][nt][2] = (__bf16)p2; pk[qa][nt][3] = (__bf16)p3;
      }

    // PV in two 32-key passes through the halved Ps
#pragma unroll
    for (int ks = 0; ks < 2; ks++) {
#pragma unroll
      for (int qa = 0; qa < 4; qa++)
#pragma unroll
        for (int nh = 0; nh < 2; nh++) {
          // key_local = nh*16 + qd*4 + reg; chunk = nh*2 + (qd>>1); half = qd&1
          int slot = ((nh * 2 + (qd >> 1)) ^ psw);
          *(uint2*)&Ps[wave][(qa * 16 + r) * 32 + slot * 8 + (qd & 1) * 4] =
              *(uint2*)&pk[qa][ks * 2 + nh];
        }
      bf16x8_t pf[4];
#pragma unroll
      for (int qa = 0; qa < 4; qa++)
        pf[qa] = *(const bf16x8_t*)&Ps[wave][(qa * 16 + r) * 32 + pck];
#pragma unroll
      for (int nt = 0; nt < 4; nt++) {
        const u16* vb = &Vs[kv][buf][(nt * 16 + r) * 64];
        bf16x8_t vf = *(const bf16x8_t*)(vb + (ks ? ck1 : ck0));
#pragma unroll
        for (int qa = 0; qa < 4; qa++)
          accO[qa][nt] = mfma16(pf[qa], vf, accO[qa][nt]);
      }
    }
  }

  // ---- combine split-K halves via LDS, normalize, store ----
  __syncthreads();
  float* Sc  = (float*)&Ks[0][0][0];   // 2 x 64x64 f32 = 32 KB
  float* Lsc = (float*)&Vs[0][0][0];
  if (kv == 1) {
#pragma unroll
    for (int qa = 0; qa < 4; qa++) {
#pragma unroll
      for (int nt = 0; nt < 4; nt++)
        *(f32x4_t*)&Sc[g * 4096 + ((qa * 4 + nt) * 64 + lane) * 4] = accO[qa][nt];
      Lsc[g * 256 + qa * 64 + lane] = Lacc[qa];
    }
  }
  __syncthreads();
  if (kv == 0) {
#pragma unroll
    for (int qa = 0; qa < 4; qa++) {
      Lacc[qa] += Lsc[g * 256 + qa * 64 + lane];
      float v = Lacc[qa];
      v += __shfl_xor(v, 16);
      v += __shfl_xor(v, 32);
      Lacc[qa] = v;
#pragma unroll
      for (int nt = 0; nt < 4; nt++) {
        f32x4_t o = *(const f32x4_t*)&Sc[g * 4096 + ((qa * 4 + nt) * 64 + lane) * 4];
        accO[qa][nt] += o;
      }
    }
#pragma unroll
    for (int qa = 0; qa < 4; qa++)
#pragma unroll
      for (int reg = 0; reg < 4; reg++) {
        float L = __shfl(Lacc[qa], qd * 4 + reg);
        float inv = 1.f / L;
        int gr = q0 + g * 64 + qa * 16 + qd * 4 + reg;
#pragma unroll
        for (int nt = 0; nt < 4; nt++)
          ((__bf16*)Oattn)[bbase + (long)gr * 512 + h * 64 + nt * 16 + r] =
              (__bf16)(accO[qa][nt][reg] * inv);
      }
  }
}

// ---------------- launch ----------------
extern "C" void kernel_launch(void* const* d_in, const int* in_sizes, int n_in,
                              void* d_out, int out_size, void* d_ws, size_t ws_size,
                              hipStream_t stream) {
  const float* x  = (const float*)d_in[0];
  const float* Wq = (const float*)d_in[1];
  const float* Wk = (const float*)d_in[2];
  const float* Wv = (const float*)d_in[3];
  const float* Wo = (const float*)d_in[4];
  const float* bo = (const float*)d_in[5];
  float* out = (float*)d_out;

  u16* ws  = (u16*)d_ws;
  u16* xb  = ws;
  u16* wqb = xb  + 4194304;
  u16* wkb = wqb + 262144;
  u16* wvb = wkb + 262144;
  u16* wob = wvb + 262144;
  u16* Qb  = wob + 262144;
  u16* Kb  = Qb  + 4194304;
  u16* Vtg = Kb  + 4194304;   // V^T: [2*512][4096]
  u16* Ab  = Vtg + 4194304;

  cast_all_kernel<<<5120, 256, 0, stream>>>(x, Wq, Wk, Wv, Wo, xb, wqb, wkb, wvb, wob);

  dim3 g1(64, 4, 3);
  gemm_qkv_kernel<<<g1, 256, 0, stream>>>(xb, wqb, wkb, wvb, Qb, Kb, Vtg);

  dim3 g2(32, 16);
  attn_kernel<<<g2, 256, 0, stream>>>(Qb, Kb, Vtg, Ab);

  dim3 g3(64, 4);
  gemm_out_kernel<<<g3, 256, 0, stream>>>(Ab, wob, out, bo);
}

// Round 6
// 197.105 us; speedup vs baseline: 1.0731x; 1.0731x over previous
//
#include <hip/hip_runtime.h>

// Problem constants: B=2, S=4096, H=8, DH=64, D=512, M = B*S = 8192.
#define LOG2E 1.44269504088896340736f

typedef unsigned short u16;
typedef short s16x4 __attribute__((ext_vector_type(4)));
typedef __bf16 bf16x4_t __attribute__((ext_vector_type(4)));
typedef __bf16 bf16x8_t __attribute__((ext_vector_type(8)));
typedef float f32x4_t __attribute__((ext_vector_type(4)));

__device__ __forceinline__ u16 f2bf(float f) {
  union { float f; unsigned int u; } v;
  v.f = f;
  unsigned int u = v.u;
  u += 0x7fffu + ((u >> 16) & 1u);
  return (u16)(u >> 16);
}

__device__ __forceinline__ f32x4_t mfma16(bf16x8_t a, bf16x8_t b, f32x4_t c) {
  return __builtin_amdgcn_mfma_f32_16x16x32_bf16(a, b, c, 0, 0, 0);
}
// 16x16x16 bf16 (A/B as 4 x i16 bit-patterns)
__device__ __forceinline__ f32x4_t mfma16x16(s16x4 a, s16x4 b, f32x4_t c) {
  return __builtin_amdgcn_mfma_f32_16x16x16bf16_1k(a, b, c, 0, 0, 0);
}

// async 16B global -> LDS (dest = wave-uniform base + lane*16)
__device__ __forceinline__ void gl_lds16(const u16* g, u16* l) {
  __builtin_amdgcn_global_load_lds(
      (const __attribute__((address_space(1))) unsigned int*)g,
      (__attribute__((address_space(3))) unsigned int*)l, 16, 0, 0);
}

// ---------------- cast fp32 -> bf16 (Wq pre-scaled by 0.125*log2e) ----------------
__global__ __launch_bounds__(256) void cast_all_kernel(
    const float* __restrict__ x, const float* __restrict__ wq, const float* __restrict__ wk,
    const float* __restrict__ wv, const float* __restrict__ wo,
    u16* __restrict__ xb, u16* __restrict__ wqb, u16* __restrict__ wkb,
    u16* __restrict__ wvb, u16* __restrict__ wob) {
  const int NX = 2 * 4096 * 512;
  const int NW = 512 * 512;
  int i = (blockIdx.x * 256 + threadIdx.x) * 4;
  const float* src; u16* dst; int off; float scale = 1.f;
  if (i < NX)               { src = x;  dst = xb;  off = i; }
  else if (i < NX + NW)     { src = wq; dst = wqb; off = i - NX; scale = 0.125f * LOG2E; }
  else if (i < NX + 2 * NW) { src = wk; dst = wkb; off = i - NX - NW; }
  else if (i < NX + 3 * NW) { src = wv; dst = wvb; off = i - NX - 2 * NW; }
  else                      { src = wo; dst = wob; off = i - NX - 3 * NW; }
  float4 f = *(const float4*)(src + off);
  unsigned int lo = (unsigned int)f2bf(f.x * scale) | ((unsigned int)f2bf(f.y * scale) << 16);
  unsigned int hi = (unsigned int)f2bf(f.z * scale) | ((unsigned int)f2bf(f.w * scale) << 16);
  uint2 o; o.x = lo; o.y = hi;
  *(uint2*)(dst + off) = o;
}

// ---------------- GEMM: C[M,N] = A[M,512] @ Bt[N,512]^T (both bf16, K-contig) ----------------
// MODE 0: bf16 row-major C. MODE 1: V^T store. MODE 2: fp32 + bias.
template <int MODE>
__device__ __forceinline__ void gemm_core(const u16* __restrict__ A, const u16* __restrict__ Bt,
                                          void* __restrict__ Cout, const float* __restrict__ bias,
                                          int Mbase, int Nbase) {
  __shared__ __align__(16) u16 As[128][40];
  __shared__ __align__(16) u16 Bs[128][40];
  const int t = threadIdx.x;
  const int wave = t >> 6, lane = t & 63;
  const int r = lane & 15, qd = lane >> 4;
  const int wm = wave & 1, wn = wave >> 1;
  const int lr = t >> 2;
  const int lc = (t & 3) * 8;

  f32x4_t acc[4][4];
#pragma unroll
  for (int i = 0; i < 4; i++)
#pragma unroll
    for (int j = 0; j < 4; j++) { f32x4_t z = {0.f, 0.f, 0.f, 0.f}; acc[i][j] = z; }

  const u16* pa0 = A  + (Mbase + lr) * 512 + lc;
  const u16* pa1 = A  + (Mbase + 64 + lr) * 512 + lc;
  const u16* pb0 = Bt + (Nbase + lr) * 512 + lc;
  const u16* pb1 = Bt + (Nbase + 64 + lr) * 512 + lc;

  uint4 ra0 = *(const uint4*)(pa0);
  uint4 ra1 = *(const uint4*)(pa1);
  uint4 rb0 = *(const uint4*)(pb0);
  uint4 rb1 = *(const uint4*)(pb1);

  for (int k0 = 0; k0 < 512; k0 += 32) {
    *(uint4*)&As[lr][lc]      = ra0;
    *(uint4*)&As[64 + lr][lc] = ra1;
    *(uint4*)&Bs[lr][lc]      = rb0;
    *(uint4*)&Bs[64 + lr][lc] = rb1;
    __syncthreads();
    if (k0 < 480) {
      ra0 = *(const uint4*)(pa0 + k0 + 32);
      ra1 = *(const uint4*)(pa1 + k0 + 32);
      rb0 = *(const uint4*)(pb0 + k0 + 32);
      rb1 = *(const uint4*)(pb1 + k0 + 32);
    }
    bf16x8_t af[4], bfr[4];
#pragma unroll
    for (int i = 0; i < 4; i++) af[i]  = *(const bf16x8_t*)&As[wm * 64 + i * 16 + r][qd * 8];
#pragma unroll
    for (int j = 0; j < 4; j++) bfr[j] = *(const bf16x8_t*)&Bs[wn * 64 + j * 16 + r][qd * 8];
#pragma unroll
    for (int i = 0; i < 4; i++)
#pragma unroll
      for (int j = 0; j < 4; j++) acc[i][j] = mfma16(af[i], bfr[j], acc[i][j]);
    __syncthreads();
  }

  float bv[4];
  if (MODE == 2) {
#pragma unroll
    for (int j = 0; j < 4; j++) bv[j] = bias[Nbase + wn * 64 + j * 16 + r];
  }
#pragma unroll
  for (int i = 0; i < 4; i++) {
#pragma unroll
    for (int reg = 0; reg < 4; reg++) {
      int gr = Mbase + wm * 64 + i * 16 + qd * 4 + reg;
#pragma unroll
      for (int j = 0; j < 4; j++) {
        int gc = Nbase + wn * 64 + j * 16 + r;
        float val = acc[i][j][reg];
        if (MODE == 2) {
          ((float*)Cout)[gr * 512 + gc] = val + bv[j];
        } else if (MODE == 1) {
          int bb = gc >> 12, ss = gc & 4095;
          ((__bf16*)Cout)[((long)(bb * 512 + gr)) * 4096 + ss] = (__bf16)val;
        } else {
          ((__bf16*)Cout)[gr * 512 + gc] = (__bf16)val;
        }
      }
    }
  }
}

__global__ __launch_bounds__(256) void gemm_qkv_kernel(
    const u16* __restrict__ X,
    const u16* __restrict__ Wq, const u16* __restrict__ Wk, const u16* __restrict__ Wv,
    u16* __restrict__ Q, u16* __restrict__ K, u16* __restrict__ Vt) {
  if (blockIdx.z == 0)
    gemm_core<0>(X, Wq, Q, nullptr, blockIdx.x * 128, blockIdx.y * 128);
  else if (blockIdx.z == 1)
    gemm_core<0>(X, Wk, K, nullptr, blockIdx.x * 128, blockIdx.y * 128);
  else
    gemm_core<1>(Wv, X, Vt, nullptr, blockIdx.y * 128, blockIdx.x * 128);
}

__global__ __launch_bounds__(256) void gemm_out_kernel(
    const u16* __restrict__ Aat, const u16* __restrict__ Wo,
    float* __restrict__ Out, const float* __restrict__ bo) {
  gemm_core<2>(Aat, Wo, Out, bo, blockIdx.x * 128, blockIdx.y * 128);
}

// ---------------- flash attention v5: register-direct P (no LDS round-trip) ----------------
// grid (32, 16), block 256 (4 waves). Wave = (g = wave&1 -> 64-query group,
// kv = wave>>1 -> 2048-key half). QK^T transposed (A=K, B=Q) -> St C-layout
// [col=query=lane&15, row=key=(lane>>4)*4+reg], which IS the B-layout of
// v_mfma_f32_16x16x16_bf16 (n=lane&15, k=(lane>>4)*4+j). PV swapped
// (O^T = V^T * P^T): P enters directly from registers. LDS: K/V dbuf 64 KiB.
__global__ __launch_bounds__(256, 2) void attn_kernel(
    const u16* __restrict__ Q, const u16* __restrict__ K, const u16* __restrict__ Vt,
    u16* __restrict__ Oattn) {
  __shared__ __align__(16) u16 Ks[2][2][4096];
  __shared__ __align__(16) u16 Vs[2][2][4096];

  const int t = threadIdx.x;
  const int wave = t >> 6, lane = t & 63;
  const int r = lane & 15, qd = lane >> 4;
  const int g = wave & 1, kv = wave >> 1;
  const int bh = blockIdx.y;
  const int b = bh >> 3, h = bh & 7;
  const long bbase = (long)b * 4096 * 512;
  const int q0 = blockIdx.x * 128;

  const int sw = r & 7;
  const int ck0 = (qd ^ sw) * 8;          // K row chunks (rows 64 u16, 8 chunks of 8)
  const int ck1 = ((qd + 4) ^ sw) * 8;
  int vck[4];                              // V^T b64 frag offsets per 16-key step
#pragma unroll
  for (int ks = 0; ks < 4; ks++)
    vck[ks] = ((ks * 2 + (qd >> 1)) ^ sw) * 8 + (qd & 1) * 4;

  // Q as B-operand fragments (resident)
  bf16x8_t qf[4][2];
#pragma unroll
  for (int qa = 0; qa < 4; qa++) {
    const u16* qp = Q + bbase + (long)(q0 + g * 64 + qa * 16 + r) * 512 + h * 64 + qd * 8;
    qf[qa][0] = *(const bf16x8_t*)(qp);
    qf[qa][1] = *(const bf16x8_t*)(qp + 32);
  }

  f32x4_t accO[4][4];   // [qa][dm]: O^T tile, col=query qa*16+r, row=d dm*16+qd*4+reg
  float Lacc[4];
#pragma unroll
  for (int qa = 0; qa < 4; qa++) {
    f32x4_t z = {0.f, 0.f, 0.f, 0.f};
    Lacc[qa] = 0.f;
#pragma unroll
    for (int nt = 0; nt < 4; nt++) accO[qa][nt] = z;
  }

  // staging: wave stages rows g*32..+31 of its kv-half's K and V tiles
  const int rr = lane >> 3;
  const int cc = (lane & 7) ^ rr;
  const u16* kgb = K + bbase + (long)(kv * 2048 + g * 32 + rr) * 512 + h * 64 + cc * 8;
  const u16* vgb = Vt + ((long)(b * 512 + h * 64 + g * 32 + rr)) * 4096 + kv * 2048 + cc * 8;

  // prologue: issue tile 0 into buf 0
#pragma unroll
  for (int i = 0; i < 4; i++) gl_lds16(kgb + (long)i * 8 * 512, &Ks[kv][0][g * 2048] + i * 512);
#pragma unroll
  for (int i = 0; i < 4; i++) gl_lds16(vgb + i * 8 * 4096, &Vs[kv][0][g * 2048] + i * 512);

  for (int it = 0; it < 32; it++) {
    const int buf = it & 1;
    __syncthreads();   // drains this tile's loads (issued one iter ago)

    if (it < 31) {     // prefetch tile it+1
      const int nb = (it + 1) & 1;
      const long ko = (long)(it + 1) * 64;
#pragma unroll
      for (int i = 0; i < 4; i++)
        gl_lds16(kgb + (ko + i * 8) * 512, &Ks[kv][nb][g * 2048] + i * 512);
#pragma unroll
      for (int i = 0; i < 4; i++)
        gl_lds16(vgb + ko + (long)i * 8 * 4096, &Vs[kv][nb][g * 2048] + i * 512);
    }

    // K as A-operand fragments (16x16x32)
    bf16x8_t kf[4][2];
#pragma unroll
    for (int nt = 0; nt < 4; nt++) {
      const u16* kb = &Ks[kv][buf][(nt * 16 + r) * 64];
      kf[nt][0] = *(const bf16x8_t*)(kb + ck0);
      kf[nt][1] = *(const bf16x8_t*)(kb + ck1);
    }

    // transposed scores St[m=key][n=query]
    f32x4_t St[4][4];
#pragma unroll
    for (int qa = 0; qa < 4; qa++)
#pragma unroll
      for (int nt = 0; nt < 4; nt++) {
        f32x4_t z = {0.f, 0.f, 0.f, 0.f};
        z = mfma16(kf[nt][0], qf[qa][0], z);
        z = mfma16(kf[nt][1], qf[qa][1], z);
        St[qa][nt] = z;
      }

    // exp2 -> P directly in B-operand layout of 16x16x16 (k = qd*4+reg)
    s16x4 pk[4][4];
#pragma unroll
    for (int qa = 0; qa < 4; qa++)
#pragma unroll
      for (int nt = 0; nt < 4; nt++) {
        float p0 = __builtin_amdgcn_exp2f(St[qa][nt][0]);
        float p1 = __builtin_amdgcn_exp2f(St[qa][nt][1]);
        float p2 = __builtin_amdgcn_exp2f(St[qa][nt][2]);
        float p3 = __builtin_amdgcn_exp2f(St[qa][nt][3]);
        Lacc[qa] += (p0 + p1) + (p2 + p3);
        bf16x4_t pb;
        pb[0] = (__bf16)p0; pb[1] = (__bf16)p1; pb[2] = (__bf16)p2; pb[3] = (__bf16)p3;
        pk[qa][nt] = *(s16x4*)&pb;
      }

    // PV swapped: accO^T[d][q] += V^T[d][k] * P^T[k][q], 16 keys per step
#pragma unroll
    for (int ks = 0; ks < 4; ks++) {
      s16x4 va[4];
#pragma unroll
      for (int dm = 0; dm < 4; dm++)
        va[dm] = *(const s16x4*)&Vs[kv][buf][(dm * 16 + r) * 64 + vck[ks]];
#pragma unroll
      for (int qa = 0; qa < 4; qa++)
#pragma unroll
        for (int dm = 0; dm < 4; dm++)
          accO[qa][dm] = mfma16x16(va[dm], pk[qa][ks], accO[qa][dm]);
    }
  }

  // ---- combine split-K halves via LDS, normalize, store ----
  __syncthreads();
  float* Sc  = (float*)&Ks[0][0][0];   // 2 x 4096 f32 = 32 KB
  float* Lsc = (float*)&Vs[0][0][0];
  if (kv == 1) {
#pragma unroll
    for (int qa = 0; qa < 4; qa++) {
#pragma unroll
      for (int dm = 0; dm < 4; dm++)
        *(f32x4_t*)&Sc[g * 4096 + ((qa * 4 + dm) * 64 + lane) * 4] = accO[qa][dm];
      Lsc[g * 256 + qa * 64 + lane] = Lacc[qa];
    }
  }
  __syncthreads();
  if (kv == 0) {
#pragma unroll
    for (int qa = 0; qa < 4; qa++) {
      Lacc[qa] += Lsc[g * 256 + qa * 64 + lane];
      float v = Lacc[qa];
      v += __shfl_xor(v, 16);
      v += __shfl_xor(v, 32);
      Lacc[qa] = v;
    }
#pragma unroll
    for (int qa = 0; qa < 4; qa++) {
      float inv = 1.f / Lacc[qa];
      int gq = q0 + g * 64 + qa * 16 + r;
#pragma unroll
      for (int dm = 0; dm < 4; dm++) {
        f32x4_t o = *(const f32x4_t*)&Sc[g * 4096 + ((qa * 4 + dm) * 64 + lane) * 4];
        o += accO[qa][dm];
        bf16x4_t ob;
#pragma unroll
        for (int reg = 0; reg < 4; reg++) ob[reg] = (__bf16)(o[reg] * inv);
        *(uint2*)&Oattn[bbase + (long)gq * 512 + h * 64 + dm * 16 + qd * 4] = *(uint2*)&ob;
      }
    }
  }
}

// ---------------- launch ----------------
extern "C" void kernel_launch(void* const* d_in, const int* in_sizes, int n_in,
                              void* d_out, int out_size, void* d_ws, size_t ws_size,
                              hipStream_t stream) {
  const float* x  = (const float*)d_in[0];
  const float* Wq = (const float*)d_in[1];
  const float* Wk = (const float*)d_in[2];
  const float* Wv = (const float*)d_in[3];
  const float* Wo = (const float*)d_in[4];
  const float* bo = (const float*)d_in[5];
  float* out = (float*)d_out;

  u16* ws  = (u16*)d_ws;
  u16* xb  = ws;
  u16* wqb = xb  + 4194304;
  u16* wkb = wqb + 262144;
  u16* wvb = wkb + 262144;
  u16* wob = wvb + 262144;
  u16* Qb  = wob + 262144;
  u16* Kb  = Qb  + 4194304;
  u16* Vtg = Kb  + 4194304;   // V^T: [2*512][4096]
  u16* Ab  = Vtg + 4194304;

  cast_all_kernel<<<5120, 256, 0, stream>>>(x, Wq, Wk, Wv, Wo, xb, wqb, wkb, wvb, wob);

  dim3 g1(64, 4, 3);
  gemm_qkv_kernel<<<g1, 256, 0, stream>>>(xb, wqb, wkb, wvb, Qb, Kb, Vtg);

  dim3 g2(32, 16);
  attn_kernel<<<g2, 256, 0, stream>>>(Qb, Kb, Vtg, Ab);

  dim3 g3(64, 4);
  gemm_out_kernel<<<g3, 256, 0, stream>>>(Ab, wob, out, bo);
}